// Round 2
// baseline (487.810 us; speedup 1.0000x reference)
//
#include <hip/hip_runtime.h>
#include <hip/hip_bf16.h>
#include <cstdint>
#include <cmath>

typedef __bf16 bf16x8 __attribute__((ext_vector_type(8)));
typedef float  f32x4  __attribute__((ext_vector_type(4)));

#define BT 128   // tile M and N
#define BK 64    // tile K

__device__ __forceinline__ float bf2f(unsigned short h) {
  union { unsigned int u; float f; } v; v.u = ((unsigned int)h) << 16;
  return v.f;
}
__device__ __forceinline__ unsigned short f2bf(float x) {
  union { float f; unsigned int u; } v; v.f = x;
  unsigned int r = v.u + 0x7fffu + ((v.u >> 16) & 1u);  // RNE
  return (unsigned short)(r >> 16);
}

__device__ __forceinline__ void gld_lds16(const void* g, void* l) {
  __builtin_amdgcn_global_load_lds(
      (const __attribute__((address_space(1))) unsigned int*)g,
      (__attribute__((address_space(3))) unsigned int*)l,
      16, 0, 0);
}

// fp32 -> bf16 conversion, 4 elems/thread
__global__ void cvt_f32_bf16(const float* __restrict__ in,
                             unsigned short* __restrict__ out, int n4) {
  int i = blockIdx.x * blockDim.x + threadIdx.x;
  if (i < n4) {
    float4 v = reinterpret_cast<const float4*>(in)[i];
    ushort4 o;
    o.x = f2bf(v.x); o.y = f2bf(v.y); o.z = f2bf(v.z); o.w = f2bf(v.w);
    reinterpret_cast<ushort4*>(out)[i] = o;
  }
}

// C[M,N] = A[M,K] * B[N,K]^T   (bf16 in, fp32 accumulate; out bf16 or fp32)
// GUARD_N: clamp B-row loads and guard C-col stores for ragged N.
template <int GUARD_N, int OUT_F32>
__global__ __launch_bounds__(256, 2)
void gemm_bt(const unsigned short* __restrict__ A,
             const unsigned short* __restrict__ B,
             void* __restrict__ Cv,
             int N, int K, int ldA, int ldB, int ldC)
{
  __shared__ __align__(16) unsigned short sA[BT * BK];
  __shared__ __align__(16) unsigned short sB[BT * BK];

  const int tid  = threadIdx.x;
  const int lane = tid & 63;
  const int wave = tid >> 6;
  const int row0 = blockIdx.x * BT;
  const int col0 = blockIdx.y * BT;

  const int wrow = (wave & 1) * 64;
  const int wcol = (wave >> 1) * 64;
  const int l15  = lane & 15;
  const int q    = lane >> 4;

  f32x4 acc[4][4];
#pragma unroll
  for (int i = 0; i < 4; ++i)
#pragma unroll
    for (int j = 0; j < 4; ++j)
      acc[i][j] = (f32x4){0.f, 0.f, 0.f, 0.f};

  const int nk = K / BK;
  for (int kt = 0; kt < nk; ++kt) {
    const int k0 = kt * BK;
#pragma unroll
    for (int t = 0; t < 4; ++t) {
      int c  = t * 256 + tid;
      int r  = c >> 3;          // tile row 0..127
      int cc = (c & 7) * 8;     // k offset 0,8,..,56
      gld_lds16(A + (size_t)(row0 + r) * ldA + k0 + cc, (void*)(sA + c * 8));
      int br = col0 + r;
      if (GUARD_N) br = (br < N) ? br : (N - 1);
      gld_lds16(B + (size_t)br * ldB + k0 + cc, (void*)(sB + c * 8));
    }
    __syncthreads();

#pragma unroll
    for (int kk = 0; kk < BK; kk += 32) {
      bf16x8 af[4], bfr[4];
#pragma unroll
      for (int i = 0; i < 4; ++i) {
        int ar = wrow + i * 16 + l15;
        af[i] = *reinterpret_cast<const bf16x8*>(sA + ar * BK + kk + q * 8);
        int br = wcol + i * 16 + l15;
        bfr[i] = *reinterpret_cast<const bf16x8*>(sB + br * BK + kk + q * 8);
      }
#pragma unroll
      for (int i = 0; i < 4; ++i)
#pragma unroll
        for (int j = 0; j < 4; ++j)
          acc[i][j] = __builtin_amdgcn_mfma_f32_16x16x32_bf16(af[i], bfr[j], acc[i][j], 0, 0, 0);
    }
    __syncthreads();
  }

  // C/D layout: col=lane&15, row=q*4+reg
#pragma unroll
  for (int i = 0; i < 4; ++i) {
#pragma unroll
    for (int j = 0; j < 4; ++j) {
      int colw = col0 + wcol + j * 16 + l15;
      if (GUARD_N && colw >= N) continue;
#pragma unroll
      for (int r = 0; r < 4; ++r) {
        int roww = row0 + wrow + i * 16 + q * 4 + r;
        if (OUT_F32)
          ((float*)Cv)[(size_t)roww * ldC + colw] = acc[i][j][r];
        else
          ((unsigned short*)Cv)[(size_t)roww * ldC + colw] = f2bf(acc[i][j][r]);
      }
    }
  }
}

// xc[bl,c] = silu(conv_b[c] + sum_k conv_w[c,k]*xb[bl+k-3, c]),  xb = xz[:, :2048]
__global__ void conv_silu_kernel(const unsigned short* __restrict__ xz,
                                 const float* __restrict__ conv_w,
                                 const float* __restrict__ conv_b,
                                 unsigned short* __restrict__ xc)
{
  const int bl = blockIdx.x;       // 0..8191
  const int l  = bl & 4095;        // position within sequence
  for (int c = threadIdx.x; c < 2048; c += 256) {
    float acc = conv_b[c];
#pragma unroll
    for (int k = 0; k < 4; ++k) {
      int ll = l + k - 3;
      if (ll >= 0)
        acc += conv_w[c * 4 + k] * bf2f(xz[(size_t)(bl + k - 3) * 4096 + c]);
    }
    float s = acc / (1.f + expf(-acc));
    xc[(size_t)bl * 2048 + c] = f2bf(s);
  }
}

// y = (softplus(delta)*xc*bc + D*xc) * silu(z); in-place over xc
__global__ void gate_kernel(const unsigned short* __restrict__ proj,  // [8192][2080]
                            const unsigned short* __restrict__ xz,    // z at col+2048
                            const float* __restrict__ Dw,             // [2048]
                            unsigned short* __restrict__ xc_y)        // [8192][2048]
{
  const int bl = blockIdx.x;
  const unsigned short* p = proj + (size_t)bl * 2080;
  float bc = 0.f;
#pragma unroll
  for (int s = 0; s < 16; ++s) bc += bf2f(p[s]) * bf2f(p[16 + s]);

  for (int c = threadIdx.x; c < 2048; c += 256) {
    float d = bf2f(p[32 + c]);
    float delta = (d > 15.f) ? d : log1pf(expf(d));
    float xcv = bf2f(xc_y[(size_t)bl * 2048 + c]);
    float zv  = bf2f(xz[(size_t)bl * 4096 + 2048 + c]);
    float y = delta * xcv * bc + Dw[c] * xcv;
    y *= zv / (1.f + expf(-zv));
    xc_y[(size_t)bl * 2048 + c] = f2bf(y);
  }
}

extern "C" void kernel_launch(void* const* d_in, const int* in_sizes, int n_in,
                              void* d_out, int out_size, void* d_ws, size_t ws_size,
                              hipStream_t stream) {
  const float* x       = (const float*)d_in[0]; // [8192][1024]
  const float* W_in    = (const float*)d_in[1]; // [4096][1024]
  const float* conv_w  = (const float*)d_in[2]; // [2048][4]
  const float* conv_b  = (const float*)d_in[3]; // [2048]
  const float* W_xproj = (const float*)d_in[4]; // [2080][2048]
  const float* Dw      = (const float*)d_in[5]; // [2048]
  const float* W_out   = (const float*)d_in[6]; // [1024][2048]
  float* out = (float*)d_out;                   // [8192][1024] fp32

  // Workspace layout (bf16 buffers), ~152.5 MiB total
  unsigned short* xz_bf   = (unsigned short*)d_ws;                 // 8192*4096
  unsigned short* xc_bf   = xz_bf  + (size_t)8192 * 4096;          // 8192*2048
  unsigned short* proj_bf = xc_bf  + (size_t)8192 * 2048;          // 8192*2080
  unsigned short* xb_bf   = proj_bf + (size_t)8192 * 2080;         // 8192*1024 (reused for W_xproj)
  unsigned short* w_bf    = xb_bf  + (size_t)8192 * 1024;          // 4096*1024 (reused for W_out)

  // 1) convert x, W_in to bf16
  cvt_f32_bf16<<<(8192 * 1024 / 4 + 255) / 256, 256, 0, stream>>>(x, xb_bf, 8192 * 1024 / 4);
  cvt_f32_bf16<<<(4096 * 1024 / 4 + 255) / 256, 256, 0, stream>>>(W_in, w_bf, 4096 * 1024 / 4);
  // 2) xz = x @ W_in^T   (M=8192, N=4096, K=1024)
  gemm_bt<0, 0><<<dim3(64, 32), 256, 0, stream>>>(xb_bf, w_bf, xz_bf, 4096, 1024, 1024, 1024, 4096);
  // 3) convert W_xproj into xb region (xb no longer needed)
  cvt_f32_bf16<<<(2080 * 2048 / 4 + 255) / 256, 256, 0, stream>>>(W_xproj, xb_bf, 2080 * 2048 / 4);
  // 4) conv + silu -> xc
  conv_silu_kernel<<<8192, 256, 0, stream>>>(xz_bf, conv_w, conv_b, xc_bf);
  // 5) proj = xc @ W_xproj^T  (N=2080 ragged -> 17 col-tiles, guarded)
  gemm_bt<1, 0><<<dim3(64, 17), 256, 0, stream>>>(xc_bf, xb_bf, proj_bf, 2080, 2048, 2048, 2048, 2080);
  // 6) convert W_out into w_bf region
  cvt_f32_bf16<<<(1024 * 2048 / 4 + 255) / 256, 256, 0, stream>>>(W_out, w_bf, 1024 * 2048 / 4);
  // 7) gate -> y (in place over xc)
  gate_kernel<<<8192, 256, 0, stream>>>(proj_bf, xz_bf, Dw, xc_bf);
  // 8) out = y @ W_out^T  (M=8192, N=1024, K=2048), fp32 out
  gemm_bt<0, 1><<<dim3(64, 8), 256, 0, stream>>>(xc_bf, w_bf, out, 1024, 2048, 2048, 2048, 1024);
}

// Round 3
// 476.512 us; speedup vs baseline: 1.0237x; 1.0237x over previous
//
#include <hip/hip_runtime.h>
#include <hip/hip_bf16.h>
#include <cstdint>
#include <cmath>

typedef __bf16 bf16x8 __attribute__((ext_vector_type(8)));
typedef float  f32x4  __attribute__((ext_vector_type(4)));

#define BT 128   // tile M and N
#define BK 64    // tile K

__device__ __forceinline__ float bf2f(unsigned short h) {
  union { unsigned int u; float f; } v; v.u = ((unsigned int)h) << 16;
  return v.f;
}
__device__ __forceinline__ unsigned short f2bf(float x) {
  union { float f; unsigned int u; } v; v.f = x;
  unsigned int r = v.u + 0x7fffu + ((v.u >> 16) & 1u);  // RNE
  return (unsigned short)(r >> 16);
}

__device__ __forceinline__ void gld_lds16(const void* g, void* l) {
  __builtin_amdgcn_global_load_lds(
      (const __attribute__((address_space(1))) unsigned int*)g,
      (__attribute__((address_space(3))) unsigned int*)l,
      16, 0, 0);
}

// fp32 -> bf16 conversion, 4 elems/thread
__global__ void cvt_f32_bf16(const float* __restrict__ in,
                             unsigned short* __restrict__ out, int n4) {
  int i = blockIdx.x * blockDim.x + threadIdx.x;
  if (i < n4) {
    float4 v = reinterpret_cast<const float4*>(in)[i];
    ushort4 o;
    o.x = f2bf(v.x); o.y = f2bf(v.y); o.z = f2bf(v.z); o.w = f2bf(v.w);
    reinterpret_cast<ushort4*>(out)[i] = o;
  }
}

// C[M,N] = A[M,K] * B[N,K]^T   (bf16 in, fp32 accumulate; out bf16 or fp32)
// LDS k-group XOR swizzle: physical slot (r,g) holds global k-group g^(r&7).
// Fragment reads then spread 16 same-q lanes across all 32 banks (2-way max,
// free per m136) instead of the unswizzled 8-way conflict on stride-128B rows.
template <int GUARD_N, int OUT_F32>
__global__ __launch_bounds__(256, 2)
void gemm_bt(const unsigned short* __restrict__ A,
             const unsigned short* __restrict__ B,
             void* __restrict__ Cv,
             int N, int K, int ldA, int ldB, int ldC)
{
  __shared__ __align__(16) unsigned short sA[BT * BK];
  __shared__ __align__(16) unsigned short sB[BT * BK];

  const int tid  = threadIdx.x;
  const int lane = tid & 63;
  const int wave = tid >> 6;
  const int row0 = blockIdx.x * BT;
  const int col0 = blockIdx.y * BT;

  const int wrow = (wave & 1) * 64;
  const int wcol = (wave >> 1) * 64;
  const int l15  = lane & 15;
  const int q    = lane >> 4;

  f32x4 acc[4][4];
#pragma unroll
  for (int i = 0; i < 4; ++i)
#pragma unroll
    for (int j = 0; j < 4; ++j)
      acc[i][j] = (f32x4){0.f, 0.f, 0.f, 0.f};

  const int nk = K / BK;
  for (int kt = 0; kt < nk; ++kt) {
    const int k0 = kt * BK;
#pragma unroll
    for (int t = 0; t < 4; ++t) {
      int c  = t * 256 + tid;
      int r  = c >> 3;               // tile row 0..127
      int g  = c & 7;                // physical k-group slot
      int gs = (g ^ (r & 7)) * 8;    // swizzled global k offset
      gld_lds16(A + (size_t)(row0 + r) * ldA + k0 + gs, (void*)(sA + c * 8));
      int br = col0 + r;
      if (GUARD_N) br = (br < N) ? br : (N - 1);
      gld_lds16(B + (size_t)br * ldB + k0 + gs, (void*)(sB + c * 8));
    }
    __syncthreads();

#pragma unroll
    for (int kk = 0; kk < BK; kk += 32) {
      const int grb = kk >> 3;  // global k-group base: 0 or 4
      bf16x8 af[4], bfr[4];
#pragma unroll
      for (int i = 0; i < 4; ++i) {
        int ar = wrow + i * 16 + l15;
        af[i] = *reinterpret_cast<const bf16x8*>(
            sA + ar * BK + (((grb + q) ^ (ar & 7)) << 3));
        int br = wcol + i * 16 + l15;
        bfr[i] = *reinterpret_cast<const bf16x8*>(
            sB + br * BK + (((grb + q) ^ (br & 7)) << 3));
      }
#pragma unroll
      for (int i = 0; i < 4; ++i)
#pragma unroll
        for (int j = 0; j < 4; ++j)
          acc[i][j] = __builtin_amdgcn_mfma_f32_16x16x32_bf16(af[i], bfr[j], acc[i][j], 0, 0, 0);
    }
    __syncthreads();
  }

  // C/D layout: col=lane&15, row=q*4+reg
#pragma unroll
  for (int i = 0; i < 4; ++i) {
#pragma unroll
    for (int j = 0; j < 4; ++j) {
      int colw = col0 + wcol + j * 16 + l15;
      if (GUARD_N && colw >= N) continue;
#pragma unroll
      for (int r = 0; r < 4; ++r) {
        int roww = row0 + wrow + i * 16 + q * 4 + r;
        if (OUT_F32)
          ((float*)Cv)[(size_t)roww * ldC + colw] = acc[i][j][r];
        else
          ((unsigned short*)Cv)[(size_t)roww * ldC + colw] = f2bf(acc[i][j][r]);
      }
    }
  }
}

// xc[bl,c] = silu(conv_b[c] + sum_k conv_w[c,k]*xb[bl+k-3, c]),  xb = xz[:, :2048]
__global__ void conv_silu_kernel(const unsigned short* __restrict__ xz,
                                 const float* __restrict__ conv_w,
                                 const float* __restrict__ conv_b,
                                 unsigned short* __restrict__ xc)
{
  const int bl = blockIdx.x;       // 0..8191
  const int l  = bl & 4095;        // position within sequence
  for (int c = threadIdx.x; c < 2048; c += 256) {
    float acc = conv_b[c];
#pragma unroll
    for (int k = 0; k < 4; ++k) {
      int ll = l + k - 3;
      if (ll >= 0)
        acc += conv_w[c * 4 + k] * bf2f(xz[(size_t)(bl + k - 3) * 4096 + c]);
    }
    float s = acc / (1.f + expf(-acc));
    xc[(size_t)bl * 2048 + c] = f2bf(s);
  }
}

// y = (softplus(delta)*xc*bc + D*xc) * silu(z); in-place over xc
__global__ void gate_kernel(const unsigned short* __restrict__ proj,  // [8192][2080]
                            const unsigned short* __restrict__ xz,    // z at col+2048
                            const float* __restrict__ Dw,             // [2048]
                            unsigned short* __restrict__ xc_y)        // [8192][2048]
{
  const int bl = blockIdx.x;
  const unsigned short* p = proj + (size_t)bl * 2080;
  float bc = 0.f;
#pragma unroll
  for (int s = 0; s < 16; ++s) bc += bf2f(p[s]) * bf2f(p[16 + s]);

  for (int c = threadIdx.x; c < 2048; c += 256) {
    float d = bf2f(p[32 + c]);
    float delta = (d > 15.f) ? d : log1pf(expf(d));
    float xcv = bf2f(xc_y[(size_t)bl * 2048 + c]);
    float zv  = bf2f(xz[(size_t)bl * 4096 + 2048 + c]);
    float y = delta * xcv * bc + Dw[c] * xcv;
    y *= zv / (1.f + expf(-zv));
    xc_y[(size_t)bl * 2048 + c] = f2bf(y);
  }
}

extern "C" void kernel_launch(void* const* d_in, const int* in_sizes, int n_in,
                              void* d_out, int out_size, void* d_ws, size_t ws_size,
                              hipStream_t stream) {
  const float* x       = (const float*)d_in[0]; // [8192][1024]
  const float* W_in    = (const float*)d_in[1]; // [4096][1024]
  const float* conv_w  = (const float*)d_in[2]; // [2048][4]
  const float* conv_b  = (const float*)d_in[3]; // [2048]
  const float* W_xproj = (const float*)d_in[4]; // [2080][2048]
  const float* Dw      = (const float*)d_in[5]; // [2048]
  const float* W_out   = (const float*)d_in[6]; // [1024][2048]
  float* out = (float*)d_out;                   // [8192][1024] fp32

  // Workspace layout (bf16 buffers), ~152.5 MiB total
  unsigned short* xz_bf   = (unsigned short*)d_ws;                 // 8192*4096
  unsigned short* xc_bf   = xz_bf  + (size_t)8192 * 4096;          // 8192*2048
  unsigned short* proj_bf = xc_bf  + (size_t)8192 * 2048;          // 8192*2080
  unsigned short* xb_bf   = proj_bf + (size_t)8192 * 2080;         // 8192*1024 (reused for W_xproj)
  unsigned short* w_bf    = xb_bf  + (size_t)8192 * 1024;          // 4096*1024 (reused for W_out)

  // 1) convert x, W_in to bf16
  cvt_f32_bf16<<<(8192 * 1024 / 4 + 255) / 256, 256, 0, stream>>>(x, xb_bf, 8192 * 1024 / 4);
  cvt_f32_bf16<<<(4096 * 1024 / 4 + 255) / 256, 256, 0, stream>>>(W_in, w_bf, 4096 * 1024 / 4);
  // 2) xz = x @ W_in^T   (M=8192, N=4096, K=1024)
  gemm_bt<0, 0><<<dim3(64, 32), 256, 0, stream>>>(xb_bf, w_bf, xz_bf, 4096, 1024, 1024, 1024, 4096);
  // 3) convert W_xproj into xb region (xb no longer needed)
  cvt_f32_bf16<<<(2080 * 2048 / 4 + 255) / 256, 256, 0, stream>>>(W_xproj, xb_bf, 2080 * 2048 / 4);
  // 4) conv + silu -> xc
  conv_silu_kernel<<<8192, 256, 0, stream>>>(xz_bf, conv_w, conv_b, xc_bf);
  // 5) proj = xc @ W_xproj^T  (N=2080 ragged -> 17 col-tiles, guarded)
  gemm_bt<1, 0><<<dim3(64, 17), 256, 0, stream>>>(xc_bf, xb_bf, proj_bf, 2080, 2048, 2048, 2048, 2080);
  // 6) convert W_out into w_bf region
  cvt_f32_bf16<<<(1024 * 2048 / 4 + 255) / 256, 256, 0, stream>>>(W_out, w_bf, 1024 * 2048 / 4);
  // 7) gate -> y (in place over xc)
  gate_kernel<<<8192, 256, 0, stream>>>(proj_bf, xz_bf, Dw, xc_bf);
  // 8) out = y @ W_out^T  (M=8192, N=1024, K=2048), fp32 out
  gemm_bt<0, 1><<<dim3(64, 8), 256, 0, stream>>>(xc_bf, w_bf, out, 1024, 2048, 2048, 2048, 1024);
}

// Round 4
// 449.649 us; speedup vs baseline: 1.0849x; 1.0597x over previous
//
#include <hip/hip_runtime.h>
#include <hip/hip_bf16.h>
#include <cstdint>
#include <cmath>

typedef __bf16 bf16x8 __attribute__((ext_vector_type(8)));
typedef float  f32x4  __attribute__((ext_vector_type(4)));
typedef unsigned short u16x8 __attribute__((ext_vector_type(8)));

#define BT 128   // tile M and N
#define BK 64    // tile K

__device__ __forceinline__ float bf2f(unsigned short h) {
  union { unsigned int u; float f; } v; v.u = ((unsigned int)h) << 16;
  return v.f;
}
__device__ __forceinline__ unsigned short f2bf(float x) {
  union { float f; unsigned int u; } v; v.f = x;
  unsigned int r = v.u + 0x7fffu + ((v.u >> 16) & 1u);  // RNE
  return (unsigned short)(r >> 16);
}

__device__ __forceinline__ void gld_lds16(const void* g, void* l) {
  __builtin_amdgcn_global_load_lds(
      (const __attribute__((address_space(1))) unsigned int*)g,
      (__attribute__((address_space(3))) unsigned int*)l,
      16, 0, 0);
}

// fp32 -> bf16 conversion, 4 elems/thread
__global__ void cvt_f32_bf16(const float* __restrict__ in,
                             unsigned short* __restrict__ out, int n4) {
  int i = blockIdx.x * blockDim.x + threadIdx.x;
  if (i < n4) {
    float4 v = reinterpret_cast<const float4*>(in)[i];
    ushort4 o;
    o.x = f2bf(v.x); o.y = f2bf(v.y); o.z = f2bf(v.z); o.w = f2bf(v.w);
    reinterpret_cast<ushort4*>(out)[i] = o;
  }
}

// C[M,N] = A[M,K] * B[N,K]^T   (bf16 in, fp32 accumulate; out bf16 or fp32)
// LDS k-group XOR swizzle: physical slot (r,g) holds global k-group g^(r&7);
// kills the 8-way bank conflict of stride-128B rows (R3: 2.67e7 -> 0).
template <int GUARD_N, int OUT_F32>
__global__ __launch_bounds__(256, 2)
void gemm_bt(const unsigned short* __restrict__ A,
             const unsigned short* __restrict__ B,
             void* __restrict__ Cv,
             int N, int K, int ldA, int ldB, int ldC)
{
  __shared__ __align__(16) unsigned short sA[BT * BK];
  __shared__ __align__(16) unsigned short sB[BT * BK];

  const int tid  = threadIdx.x;
  const int lane = tid & 63;
  const int wave = tid >> 6;
  const int row0 = blockIdx.x * BT;
  const int col0 = blockIdx.y * BT;

  const int wrow = (wave & 1) * 64;
  const int wcol = (wave >> 1) * 64;
  const int l15  = lane & 15;
  const int q    = lane >> 4;

  f32x4 acc[4][4];
#pragma unroll
  for (int i = 0; i < 4; ++i)
#pragma unroll
    for (int j = 0; j < 4; ++j)
      acc[i][j] = (f32x4){0.f, 0.f, 0.f, 0.f};

  const int nk = K / BK;
  for (int kt = 0; kt < nk; ++kt) {
    const int k0 = kt * BK;
#pragma unroll
    for (int t = 0; t < 4; ++t) {
      int c  = t * 256 + tid;
      int r  = c >> 3;               // tile row 0..127
      int g  = c & 7;                // physical k-group slot
      int gs = (g ^ (r & 7)) * 8;    // swizzled global k offset
      gld_lds16(A + (size_t)(row0 + r) * ldA + k0 + gs, (void*)(sA + c * 8));
      int br = col0 + r;
      if (GUARD_N) br = (br < N) ? br : (N - 1);
      gld_lds16(B + (size_t)br * ldB + k0 + gs, (void*)(sB + c * 8));
    }
    __syncthreads();

#pragma unroll
    for (int kk = 0; kk < BK; kk += 32) {
      const int grb = kk >> 3;  // global k-group base: 0 or 4
      bf16x8 af[4], bfr[4];
#pragma unroll
      for (int i = 0; i < 4; ++i) {
        int ar = wrow + i * 16 + l15;
        af[i] = *reinterpret_cast<const bf16x8*>(
            sA + ar * BK + (((grb + q) ^ (ar & 7)) << 3));
        int br = wcol + i * 16 + l15;
        bfr[i] = *reinterpret_cast<const bf16x8*>(
            sB + br * BK + (((grb + q) ^ (br & 7)) << 3));
      }
#pragma unroll
      for (int i = 0; i < 4; ++i)
#pragma unroll
        for (int j = 0; j < 4; ++j)
          acc[i][j] = __builtin_amdgcn_mfma_f32_16x16x32_bf16(af[i], bfr[j], acc[i][j], 0, 0, 0);
    }
    __syncthreads();
  }

  // C/D layout: col=lane&15, row=q*4+reg
#pragma unroll
  for (int i = 0; i < 4; ++i) {
#pragma unroll
    for (int j = 0; j < 4; ++j) {
      int colw = col0 + wcol + j * 16 + l15;
      if (GUARD_N && colw >= N) continue;
#pragma unroll
      for (int r = 0; r < 4; ++r) {
        int roww = row0 + wrow + i * 16 + q * 4 + r;
        if (OUT_F32)
          ((float*)Cv)[(size_t)roww * ldC + colw] = acc[i][j][r];
        else
          ((unsigned short*)Cv)[(size_t)roww * ldC + colw] = f2bf(acc[i][j][r]);
      }
    }
  }
}

// xc[bl,c] = silu(conv_b[c] + sum_k conv_w[c,k]*xb[bl+k-3, c]),  xb = xz[:, :2048]
// Vectorized: thread owns 8 contiguous channels (16B bf16 loads/stores).
__global__ void conv_silu_kernel(const unsigned short* __restrict__ xz,
                                 const float* __restrict__ conv_w,   // [2048][4]
                                 const float* __restrict__ conv_b,
                                 unsigned short* __restrict__ xc)
{
  const int bl = blockIdx.x;       // 0..8191
  const int l  = bl & 4095;        // position within sequence
  const int c0 = threadIdx.x * 8;  // 256 threads * 8 = 2048 channels

  float4 w[8];
  float acc[8];
#pragma unroll
  for (int j = 0; j < 8; ++j) {
    w[j] = reinterpret_cast<const float4*>(conv_w)[c0 + j];  // conv_w row c0+j
    acc[j] = conv_b[c0 + j];
  }
#pragma unroll
  for (int k = 0; k < 4; ++k) {
    int ll = l + k - 3;
    if (ll >= 0) {
      u16x8 v = *reinterpret_cast<const u16x8*>(xz + (size_t)(bl + k - 3) * 4096 + c0);
#pragma unroll
      for (int j = 0; j < 8; ++j)
        acc[j] += reinterpret_cast<const float*>(&w[j])[k] * bf2f(v[j]);
    }
  }
  u16x8 o;
#pragma unroll
  for (int j = 0; j < 8; ++j) {
    float s = acc[j] / (1.f + expf(-acc[j]));
    o[j] = f2bf(s);
  }
  *reinterpret_cast<u16x8*>(xc + (size_t)bl * 2048 + c0) = o;
}

// y = (softplus(delta)*xc*bc + D*xc) * silu(z); in-place over xc. Vectorized 8/thread.
__global__ void gate_kernel(const unsigned short* __restrict__ proj,  // [8192][2080]
                            const unsigned short* __restrict__ xz,    // z at col+2048
                            const float* __restrict__ Dw,             // [2048]
                            unsigned short* __restrict__ xc_y)        // [8192][2048]
{
  const int bl = blockIdx.x;
  const unsigned short* p = proj + (size_t)bl * 2080;
  float bc = 0.f;
#pragma unroll
  for (int s = 0; s < 16; ++s) bc += bf2f(p[s]) * bf2f(p[16 + s]);  // same addr all lanes -> broadcast

  const int c0 = threadIdx.x * 8;
  u16x8 dv  = *reinterpret_cast<const u16x8*>(p + 32 + c0);
  u16x8 xcv = *reinterpret_cast<const u16x8*>(xc_y + (size_t)bl * 2048 + c0);
  u16x8 zv  = *reinterpret_cast<const u16x8*>(xz + (size_t)bl * 4096 + 2048 + c0);
  float4 d0 = reinterpret_cast<const float4*>(Dw)[c0 / 4];
  float4 d1 = reinterpret_cast<const float4*>(Dw)[c0 / 4 + 1];
  const float* dd0 = reinterpret_cast<const float*>(&d0);
  const float* dd1 = reinterpret_cast<const float*>(&d1);

  u16x8 o;
#pragma unroll
  for (int j = 0; j < 8; ++j) {
    float d = bf2f(dv[j]);
    float delta = (d > 15.f) ? d : log1pf(expf(d));
    float xv = bf2f(xcv[j]);
    float z  = bf2f(zv[j]);
    float Dj = (j < 4) ? dd0[j] : dd1[j - 4];
    float y = delta * xv * bc + Dj * xv;
    y *= z / (1.f + expf(-z));
    o[j] = f2bf(y);
  }
  *reinterpret_cast<u16x8*>(xc_y + (size_t)bl * 2048 + c0) = o;
}

extern "C" void kernel_launch(void* const* d_in, const int* in_sizes, int n_in,
                              void* d_out, int out_size, void* d_ws, size_t ws_size,
                              hipStream_t stream) {
  const float* x       = (const float*)d_in[0]; // [8192][1024]
  const float* W_in    = (const float*)d_in[1]; // [4096][1024]
  const float* conv_w  = (const float*)d_in[2]; // [2048][4]
  const float* conv_b  = (const float*)d_in[3]; // [2048]
  const float* W_xproj = (const float*)d_in[4]; // [2080][2048]
  const float* Dw      = (const float*)d_in[5]; // [2048]
  const float* W_out   = (const float*)d_in[6]; // [1024][2048]
  float* out = (float*)d_out;                   // [8192][1024] fp32

  // Workspace layout (bf16 buffers), ~152.5 MiB total
  unsigned short* xz_bf   = (unsigned short*)d_ws;                 // 8192*4096
  unsigned short* xc_bf   = xz_bf  + (size_t)8192 * 4096;          // 8192*2048
  unsigned short* proj_bf = xc_bf  + (size_t)8192 * 2048;          // 8192*2080
  unsigned short* xb_bf   = proj_bf + (size_t)8192 * 2080;         // 8192*1024 (reused for W_xproj)
  unsigned short* w_bf    = xb_bf  + (size_t)8192 * 1024;          // 4096*1024 (reused for W_out)

  // 1) convert x, W_in to bf16
  cvt_f32_bf16<<<(8192 * 1024 / 4 + 255) / 256, 256, 0, stream>>>(x, xb_bf, 8192 * 1024 / 4);
  cvt_f32_bf16<<<(4096 * 1024 / 4 + 255) / 256, 256, 0, stream>>>(W_in, w_bf, 4096 * 1024 / 4);
  // 2) xz = x @ W_in^T   (M=8192, N=4096, K=1024)
  gemm_bt<0, 0><<<dim3(64, 32), 256, 0, stream>>>(xb_bf, w_bf, xz_bf, 4096, 1024, 1024, 1024, 4096);
  // 3) convert W_xproj into xb region (xb no longer needed)
  cvt_f32_bf16<<<(2080 * 2048 / 4 + 255) / 256, 256, 0, stream>>>(W_xproj, xb_bf, 2080 * 2048 / 4);
  // 4) conv + silu -> xc
  conv_silu_kernel<<<8192, 256, 0, stream>>>(xz_bf, conv_w, conv_b, xc_bf);
  // 5) proj = xc @ W_xproj^T  (N=2080 ragged -> 17 col-tiles, guarded)
  gemm_bt<1, 0><<<dim3(64, 17), 256, 0, stream>>>(xc_bf, xb_bf, proj_bf, 2080, 2048, 2048, 2048, 2080);
  // 6) convert W_out into w_bf region
  cvt_f32_bf16<<<(1024 * 2048 / 4 + 255) / 256, 256, 0, stream>>>(W_out, w_bf, 1024 * 2048 / 4);
  // 7) gate -> y (in place over xc)
  gate_kernel<<<8192, 256, 0, stream>>>(proj_bf, xz_bf, Dw, xc_bf);
  // 8) out = y @ W_out^T  (M=8192, N=1024, K=2048), fp32 out
  gemm_bt<0, 1><<<dim3(64, 8), 256, 0, stream>>>(xc_bf, w_bf, out, 1024, 2048, 2048, 2048, 1024);
}

// Round 5
// 390.394 us; speedup vs baseline: 1.2495x; 1.1518x over previous
//
#include <hip/hip_runtime.h>
#include <hip/hip_bf16.h>
#include <cstdint>
#include <cmath>

typedef __bf16 bf16x8 __attribute__((ext_vector_type(8)));
typedef float  f32x4  __attribute__((ext_vector_type(4)));
typedef unsigned short u16x8 __attribute__((ext_vector_type(8)));

#define BT 128   // tile M and N
#define BK 64    // tile K

__device__ __forceinline__ float bf2f(unsigned short h) {
  union { unsigned int u; float f; } v; v.u = ((unsigned int)h) << 16;
  return v.f;
}
__device__ __forceinline__ unsigned short f2bf(float x) {
  union { float f; unsigned int u; } v; v.f = x;
  unsigned int r = v.u + 0x7fffu + ((v.u >> 16) & 1u);  // RNE
  return (unsigned short)(r >> 16);
}

__device__ __forceinline__ void gld_lds16(const void* g, void* l) {
  __builtin_amdgcn_global_load_lds(
      (const __attribute__((address_space(1))) unsigned int*)g,
      (__attribute__((address_space(3))) unsigned int*)l,
      16, 0, 0);
}

__device__ __forceinline__ void cvt4(const float* __restrict__ in,
                                     unsigned short* __restrict__ out, int i) {
  float4 v = reinterpret_cast<const float4*>(in)[i];
  ushort4 o;
  o.x = f2bf(v.x); o.y = f2bf(v.y); o.z = f2bf(v.z); o.w = f2bf(v.w);
  reinterpret_cast<ushort4*>(out)[i] = o;
}

// Head: convert x (8192 blocks) and W_in (4096 blocks) in one launch.
__global__ void cvt_head(const float* __restrict__ x, unsigned short* __restrict__ xb,
                         const float* __restrict__ W_in, unsigned short* __restrict__ wb) {
  int b = blockIdx.x;
  if (b < 8192) cvt4(x, xb, b * 256 + threadIdx.x);
  else          cvt4(W_in, wb, (b - 8192) * 256 + threadIdx.x);
}

// Conv strip: thread owns 8 channels x 32 rows, 3-tap history in registers.
// Each xz row is fetched exactly once (vs 4x in the naive form).
__device__ void conv_strip(const unsigned short* __restrict__ xz,
                           const float* __restrict__ conv_w,
                           const float* __restrict__ conv_b,
                           unsigned short* __restrict__ xc,
                           int strip, int tid) {
  const int bl0  = strip * 32;
  const int seq0 = bl0 & ~4095;      // sequence start (B=2, L=4096)
  const int c0   = tid * 8;
  float w[4][8], bb[8];
#pragma unroll
  for (int j = 0; j < 8; ++j) {
    float4 wr = reinterpret_cast<const float4*>(conv_w)[c0 + j];
    w[0][j] = wr.x; w[1][j] = wr.y; w[2][j] = wr.z; w[3][j] = wr.w;
    bb[j] = conv_b[c0 + j];
  }
  float win[3][8];
#pragma unroll
  for (int i = 0; i < 3; ++i) {
    int r = bl0 - 3 + i;
    if (r >= seq0) {
      u16x8 v = *reinterpret_cast<const u16x8*>(xz + (size_t)r * 4096 + c0);
#pragma unroll
      for (int j = 0; j < 8; ++j) win[i][j] = bf2f(v[j]);
    } else {
#pragma unroll
      for (int j = 0; j < 8; ++j) win[i][j] = 0.f;  // zero-pad == skipped tap
    }
  }
  for (int i = 0; i < 32; ++i) {
    const int bl = bl0 + i;
    u16x8 v = *reinterpret_cast<const u16x8*>(xz + (size_t)bl * 4096 + c0);
    u16x8 o;
#pragma unroll
    for (int j = 0; j < 8; ++j) {
      float cur = bf2f(v[j]);
      float a = bb[j] + w[0][j] * win[0][j] + w[1][j] * win[1][j]
                      + w[2][j] * win[2][j] + w[3][j] * cur;
      o[j] = f2bf(a / (1.f + expf(-a)));
      win[0][j] = win[1][j]; win[1][j] = win[2][j]; win[2][j] = cur;
    }
    *reinterpret_cast<u16x8*>(xc + (size_t)bl * 2048 + c0) = o;
  }
}

// Mid: conv_silu (256 strips) + W_xproj cvt (4160 blocks) + W_out cvt (2048 blocks),
// all independent, all dep only on GEMM1. One launch instead of three.
__global__ void mid_fused(const unsigned short* __restrict__ xz,
                          const float* __restrict__ conv_w,
                          const float* __restrict__ conv_b,
                          unsigned short* __restrict__ xc,
                          const float* __restrict__ W_xproj, unsigned short* __restrict__ wx_bf,
                          const float* __restrict__ W_out,   unsigned short* __restrict__ wo_bf) {
  int b = blockIdx.x;
  if (b < 256) { conv_strip(xz, conv_w, conv_b, xc, b, threadIdx.x); return; }
  b -= 256;
  if (b < 4160) { cvt4(W_xproj, wx_bf, b * 256 + threadIdx.x); return; }  // 2080*2048/4
  cvt4(W_out, wo_bf, (b - 4160) * 256 + threadIdx.x);                      // 1024*2048/4
}

// C[M,N] = A[M,K] * B[N,K]^T   (bf16 in, fp32 accumulate; out bf16 or fp32)
// LDS k-group XOR swizzle: physical slot (r,g) holds global k-group g^(r&7);
// kills the 8-way bank conflict of stride-128B rows (R3: 2.67e7 -> 0).
template <int GUARD_N, int OUT_F32>
__global__ __launch_bounds__(256, 2)
void gemm_bt(const unsigned short* __restrict__ A,
             const unsigned short* __restrict__ B,
             void* __restrict__ Cv,
             int N, int K, int ldA, int ldB, int ldC)
{
  __shared__ __align__(16) unsigned short sA[BT * BK];
  __shared__ __align__(16) unsigned short sB[BT * BK];

  const int tid  = threadIdx.x;
  const int lane = tid & 63;
  const int wave = tid >> 6;
  const int row0 = blockIdx.x * BT;
  const int col0 = blockIdx.y * BT;

  const int wrow = (wave & 1) * 64;
  const int wcol = (wave >> 1) * 64;
  const int l15  = lane & 15;
  const int q    = lane >> 4;

  f32x4 acc[4][4];
#pragma unroll
  for (int i = 0; i < 4; ++i)
#pragma unroll
    for (int j = 0; j < 4; ++j)
      acc[i][j] = (f32x4){0.f, 0.f, 0.f, 0.f};

  const int nk = K / BK;
  for (int kt = 0; kt < nk; ++kt) {
    const int k0 = kt * BK;
#pragma unroll
    for (int t = 0; t < 4; ++t) {
      int c  = t * 256 + tid;
      int r  = c >> 3;               // tile row 0..127
      int g  = c & 7;                // physical k-group slot
      int gs = (g ^ (r & 7)) * 8;    // swizzled global k offset
      gld_lds16(A + (size_t)(row0 + r) * ldA + k0 + gs, (void*)(sA + c * 8));
      int br = col0 + r;
      if (GUARD_N) br = (br < N) ? br : (N - 1);
      gld_lds16(B + (size_t)br * ldB + k0 + gs, (void*)(sB + c * 8));
    }
    __syncthreads();

#pragma unroll
    for (int kk = 0; kk < BK; kk += 32) {
      const int grb = kk >> 3;  // global k-group base: 0 or 4
      bf16x8 af[4], bfr[4];
#pragma unroll
      for (int i = 0; i < 4; ++i) {
        int ar = wrow + i * 16 + l15;
        af[i] = *reinterpret_cast<const bf16x8*>(
            sA + ar * BK + (((grb + q) ^ (ar & 7)) << 3));
        int br = wcol + i * 16 + l15;
        bfr[i] = *reinterpret_cast<const bf16x8*>(
            sB + br * BK + (((grb + q) ^ (br & 7)) << 3));
      }
#pragma unroll
      for (int i = 0; i < 4; ++i)
#pragma unroll
        for (int j = 0; j < 4; ++j)
          acc[i][j] = __builtin_amdgcn_mfma_f32_16x16x32_bf16(af[i], bfr[j], acc[i][j], 0, 0, 0);
    }
    __syncthreads();
  }

  // C/D layout: col=lane&15, row=q*4+reg
#pragma unroll
  for (int i = 0; i < 4; ++i) {
#pragma unroll
    for (int j = 0; j < 4; ++j) {
      int colw = col0 + wcol + j * 16 + l15;
      if (GUARD_N && colw >= N) continue;
#pragma unroll
      for (int r = 0; r < 4; ++r) {
        int roww = row0 + wrow + i * 16 + q * 4 + r;
        if (OUT_F32)
          ((float*)Cv)[(size_t)roww * ldC + colw] = acc[i][j][r];
        else
          ((unsigned short*)Cv)[(size_t)roww * ldC + colw] = f2bf(acc[i][j][r]);
      }
    }
  }
}

// y = (softplus(delta)*xc*bc + D*xc) * silu(z); in-place over xc. 8/thread.
__global__ void gate_kernel(const unsigned short* __restrict__ proj,  // [8192][2080]
                            const unsigned short* __restrict__ xz,    // z at col+2048
                            const float* __restrict__ Dw,             // [2048]
                            unsigned short* __restrict__ xc_y)        // [8192][2048]
{
  const int bl = blockIdx.x;
  const unsigned short* p = proj + (size_t)bl * 2080;
  u16x8 pb0 = *reinterpret_cast<const u16x8*>(p);
  u16x8 pb1 = *reinterpret_cast<const u16x8*>(p + 8);
  u16x8 pc0 = *reinterpret_cast<const u16x8*>(p + 16);
  u16x8 pc1 = *reinterpret_cast<const u16x8*>(p + 24);
  float bc = 0.f;
#pragma unroll
  for (int s = 0; s < 8; ++s)
    bc += bf2f(pb0[s]) * bf2f(pc0[s]) + bf2f(pb1[s]) * bf2f(pc1[s]);

  const int c0 = threadIdx.x * 8;
  u16x8 dv  = *reinterpret_cast<const u16x8*>(p + 32 + c0);
  u16x8 xcv = *reinterpret_cast<const u16x8*>(xc_y + (size_t)bl * 2048 + c0);
  u16x8 zv  = *reinterpret_cast<const u16x8*>(xz + (size_t)bl * 4096 + 2048 + c0);
  float4 d0 = reinterpret_cast<const float4*>(Dw)[c0 / 4];
  float4 d1 = reinterpret_cast<const float4*>(Dw)[c0 / 4 + 1];
  const float* dd0 = reinterpret_cast<const float*>(&d0);
  const float* dd1 = reinterpret_cast<const float*>(&d1);

  u16x8 o;
#pragma unroll
  for (int j = 0; j < 8; ++j) {
    float d = bf2f(dv[j]);
    float delta = (d > 15.f) ? d : log1pf(expf(d));
    float xv = bf2f(xcv[j]);
    float z  = bf2f(zv[j]);
    float Dj = (j < 4) ? dd0[j] : dd1[j - 4];
    float y = delta * xv * bc + Dj * xv;
    y *= z / (1.f + expf(-z));
    o[j] = f2bf(y);
  }
  *reinterpret_cast<u16x8*>(xc_y + (size_t)bl * 2048 + c0) = o;
}

extern "C" void kernel_launch(void* const* d_in, const int* in_sizes, int n_in,
                              void* d_out, int out_size, void* d_ws, size_t ws_size,
                              hipStream_t stream) {
  const float* x       = (const float*)d_in[0]; // [8192][1024]
  const float* W_in    = (const float*)d_in[1]; // [4096][1024]
  const float* conv_w  = (const float*)d_in[2]; // [2048][4]
  const float* conv_b  = (const float*)d_in[3]; // [2048]
  const float* W_xproj = (const float*)d_in[4]; // [2080][2048]
  const float* Dw      = (const float*)d_in[5]; // [2048]
  const float* W_out   = (const float*)d_in[6]; // [1024][2048]
  float* out = (float*)d_out;                   // [8192][1024] fp32

  // Workspace layout (bf16 buffers), ~152.5 MiB total
  unsigned short* xz_bf   = (unsigned short*)d_ws;                 // 8192*4096
  unsigned short* xc_bf   = xz_bf  + (size_t)8192 * 4096;          // 8192*2048
  unsigned short* proj_bf = xc_bf  + (size_t)8192 * 2048;          // 8192*2080
  unsigned short* xb_bf   = proj_bf + (size_t)8192 * 2080;         // 8192*1024 (reused for W_xproj)
  unsigned short* w_bf    = xb_bf  + (size_t)8192 * 1024;          // 4096*1024 (reused for W_out)

  // 1) convert x + W_in (one launch)
  cvt_head<<<8192 + 4096, 256, 0, stream>>>(x, xb_bf, W_in, w_bf);
  // 2) xz = x @ W_in^T   (M=8192, N=4096, K=1024)
  gemm_bt<0, 0><<<dim3(64, 32), 256, 0, stream>>>(xb_bf, w_bf, xz_bf, 4096, 1024, 1024, 1024, 4096);
  // 3) conv+silu -> xc, W_xproj -> xb region, W_out -> w_bf region (one launch)
  mid_fused<<<256 + 4160 + 2048, 256, 0, stream>>>(xz_bf, conv_w, conv_b, xc_bf,
                                                   W_xproj, xb_bf, W_out, w_bf);
  // 4) proj = xc @ W_xproj^T  (N=2080 ragged -> 17 col-tiles, guarded)
  gemm_bt<1, 0><<<dim3(64, 17), 256, 0, stream>>>(xc_bf, xb_bf, proj_bf, 2080, 2048, 2048, 2048, 2080);
  // 5) gate -> y (in place over xc)
  gate_kernel<<<8192, 256, 0, stream>>>(proj_bf, xz_bf, Dw, xc_bf);
  // 6) out = y @ W_out^T  (M=8192, N=1024, K=2048), fp32 out
  gemm_bt<0, 1><<<dim3(64, 8), 256, 0, stream>>>(xc_bf, w_bf, out, 1024, 2048, 2048, 2048, 1024);
}